// Round 8
// baseline (1789.867 us; speedup 1.0000x reference)
//
#include <hip/hip_runtime.h>
#include <cstdint>
#include <cmath>

// Shapes (fixed by the problem)
#define LQ   999      // conv output length (8000-16)/8+1
#define BLQ  1998     // BATCH * LQ
#define NCH  256      // encoder channels
#define NLTOT 255744  // NCH*LQ (per batch)
#define NCHK 16       // scan chunks per sequence
#define CHL  64       // chunk length (16*64=1024 >= 999)

typedef __attribute__((ext_vector_type(8))) short bf16x8;
typedef __attribute__((ext_vector_type(4))) float f32x4;

__device__ inline ushort f2bf(float f) {
  uint32_t u = __float_as_uint(f);
  u += 0x7fff + ((u >> 16) & 1);
  return (ushort)(u >> 16);
}

__device__ inline float softplusf(float x) {
  return fmaxf(x, 0.f) + log1pf(expf(-fabsf(x)));
}

// -------------------- one-time weight quantize / transpose --------------------
__global__ __launch_bounds__(256) void k_quant(const float* __restrict__ inw,
                                               const float* __restrict__ outw,
                                               const float* __restrict__ dtw,
                                               ushort* __restrict__ inwh,
                                               ushort* __restrict__ outwh,
                                               float* __restrict__ dtwt) {
  int i = blockIdx.x * 256 + threadIdx.x;
  if (i < 4194304) inwh[i] = f2bf(inw[i]);
  if (i < 2097152) outwh[i] = f2bf(outw[i]);
  if (i < 131072) {
    int w = i >> 13, d = (i >> 4) & 511, q = i & 15;
    dtwt[(w << 13) + q * 512 + d] = dtw[i];
  }
}

// -------------------- encoder conv + relu + per-block groupnorm partials --------------------
__global__ __launch_bounds__(256) void k_enc(const float* __restrict__ mix,
                                             const float* __restrict__ ew,
                                             float* __restrict__ mw,
                                             float* __restrict__ pp) {
  int t = threadIdx.x;
  int b = blockIdx.x >= LQ;
  int rem = (blockIdx.x - b * LQ) * 256 + t;
  int n = rem / LQ;
  int l = rem - n * LQ;
  const float* mp = mix + b * 8000 + l * 8;
  const float* wp = ew + n * 16;
  float acc = 0.f;
#pragma unroll
  for (int k = 0; k < 16; ++k) acc += mp[k] * wp[k];
  float v = fmaxf(acc, 0.f);
  mw[(b * NCH + n) * LQ + l] = v;
  float s1 = v, s2 = v * v;
#pragma unroll
  for (int off = 32; off >= 1; off >>= 1) {
    s1 += __shfl_xor(s1, off, 64);
    s2 += __shfl_xor(s2, off, 64);
  }
  __shared__ float r1[4], r2[4];
  int wv = t >> 6, lane = t & 63;
  if (lane == 0) { r1[wv] = s1; r2[wv] = s2; }
  __syncthreads();
  if (t == 0) {
    pp[blockIdx.x * 2 + 0] = r1[0] + r1[1] + r1[2] + r1[3];
    pp[blockIdx.x * 2 + 1] = r2[0] + r2[1] + r2[2] + r2[3];
  }
}

// reduce per-block partials -> mean / invstd per batch (grid = 2 blocks)
__global__ __launch_bounds__(256) void k_stats(const float* __restrict__ pp,
                                               float* __restrict__ stats) {
  int t = threadIdx.x;
  int b = blockIdx.x;
  float s1 = 0.f, s2 = 0.f;
  for (int i = t; i < LQ; i += 256) {
    s1 += pp[(b * LQ + i) * 2 + 0];
    s2 += pp[(b * LQ + i) * 2 + 1];
  }
#pragma unroll
  for (int off = 32; off >= 1; off >>= 1) {
    s1 += __shfl_xor(s1, off, 64);
    s2 += __shfl_xor(s2, off, 64);
  }
  __shared__ float r1[4], r2[4];
  int wv = t >> 6, lane = t & 63;
  if (lane == 0) { r1[wv] = s1; r2[wv] = s2; }
  __syncthreads();
  if (t == 0) {
    float S1 = r1[0] + r1[1] + r1[2] + r1[3];
    float S2 = r2[0] + r2[1] + r2[2] + r2[3];
    float mu = S1 / (float)NLTOT;
    float var = S2 / (float)NLTOT - mu * mu;
    stats[4 + b * 2] = mu;
    stats[5 + b * 2] = 1.f / sqrtf(var + 1e-5f);
  }
}

__global__ __launch_bounds__(256) void k_prep(const float* __restrict__ bw,
                                              const float* __restrict__ gw,
                                              const float* __restrict__ gb,
                                              const float* __restrict__ bb,
                                              const float* __restrict__ stats,
                                              float* __restrict__ w2,
                                              float* __restrict__ cc) {
  int o = blockIdx.x, n = threadIdx.x;
  float bwv = bw[o * 256 + n];
  float w2v = bwv * gw[n];
  w2[o * 256 + n] = w2v;
  float s1 = bwv * gb[n], s2 = w2v;
#pragma unroll
  for (int off = 32; off >= 1; off >>= 1) {
    s1 += __shfl_xor(s1, off, 64);
    s2 += __shfl_xor(s2, off, 64);
  }
  __shared__ float r1[4], r2[4];
  int wv = n >> 6, lane = n & 63;
  if (lane == 0) { r1[wv] = s1; r2[wv] = s2; }
  __syncthreads();
  if (n == 0) {
    float a1 = r1[0] + r1[1] + r1[2] + r1[3];
    float a2 = r2[0] + r2[1] + r2[2] + r2[3];
    for (int b = 0; b < 2; ++b)
      cc[b * 256 + o] = bb[o] + a1 - stats[4 + b * 2] * stats[5 + b * 2] * a2;
  }
}

// -------------------- rmsnorm over last dim (256); BF=true writes bf16 --------------------
template <bool BF>
__global__ __launch_bounds__(256) void k_rms(const float* __restrict__ x,
                                             const float* __restrict__ w,
                                             float* __restrict__ out,
                                             ushort* __restrict__ outh) {
  int t = threadIdx.x;
  int row = blockIdx.x * 4 + (t >> 6);
  int lane = t & 63;
  if (row >= BLQ) return;
  float4 v = *(const float4*)&x[row * 256 + lane * 4];
  float ss = v.x * v.x + v.y * v.y + v.z * v.z + v.w * v.w;
#pragma unroll
  for (int off = 32; off >= 1; off >>= 1) ss += __shfl_xor(ss, off, 64);
  float r = 1.f / sqrtf(ss * (1.f / 256.f) + 1e-5f);
  float4 wv = *(const float4*)&w[lane * 4];
  float4 o;
  o.x = v.x * wv.x * r; o.y = v.y * wv.y * r;
  o.z = v.z * wv.z * r; o.w = v.w * wv.w * r;
  if (BF) {
    ushort4 oh = {f2bf(o.x), f2bf(o.y), f2bf(o.z), f2bf(o.w)};
    *(ushort4*)&outh[row * 256 + lane * 4] = oh;
  } else {
    *(float4*)&out[row * 256 + lane * 4] = o;
  }
}

// -------------------- generic 64x64 tiled fp32 GEMM, C = A * B^T --------------------
// MODE 0: bottleneck  A=mw (col-gather + norm fold), B=w2, C=x (256)
// MODE 3: masks       A=xn (row-major), B=mask_w, epilogue relu*mw -> masked_t[bl][256]
template <int MODE>
__global__ __launch_bounds__(256) void gemm64(const float* __restrict__ A,
                                              const float* __restrict__ Bw,
                                              float* __restrict__ C,
                                              const float* __restrict__ aux1,
                                              const float* __restrict__ aux2,
                                              int M, int K) {
  __shared__ float As[16][68];
  __shared__ float Bs[16][68];
  int t = threadIdx.x;
  int m0 = blockIdx.x * 64, n0 = blockIdx.y * 64;
  int tx = t & 15, ty = t >> 4;
  float acc[4][4] = {};
  for (int kk = 0; kk < K; kk += 16) {
    if (MODE == 0) {
#pragma unroll
      for (int j = 0; j < 4; ++j) {
        int e = t + 256 * j;
        int m_ = e & 63, k_ = e >> 6;
        int m = m0 + m_;
        float v = 0.f;
        if (m < M) {
          int bb = m >= LQ;
          int l = m - bb * LQ;
          v = A[(size_t)((bb << 8) + kk + k_) * LQ + l];
        }
        As[k_][m_] = v;
      }
    } else {
      int m_ = t >> 2, k4 = (t & 3) * 4;
      int m = m0 + m_;
      float4 v = make_float4(0.f, 0.f, 0.f, 0.f);
      if (m < M) v = *(const float4*)&A[(size_t)m * K + kk + k4];
      As[k4 + 0][m_] = v.x; As[k4 + 1][m_] = v.y;
      As[k4 + 2][m_] = v.z; As[k4 + 3][m_] = v.w;
    }
    {
      int n_ = t >> 2, k4 = (t & 3) * 4;
      int n = n0 + n_;
      float4 v = *(const float4*)&Bw[(size_t)n * K + kk + k4];
      Bs[k4 + 0][n_] = v.x; Bs[k4 + 1][n_] = v.y;
      Bs[k4 + 2][n_] = v.z; Bs[k4 + 3][n_] = v.w;
    }
    __syncthreads();
#pragma unroll
    for (int k = 0; k < 16; ++k) {
      float4 av = *(const float4*)&As[k][ty * 4];
      float4 bv = *(const float4*)&Bs[k][tx * 4];
      acc[0][0] += av.x * bv.x; acc[0][1] += av.x * bv.y; acc[0][2] += av.x * bv.z; acc[0][3] += av.x * bv.w;
      acc[1][0] += av.y * bv.x; acc[1][1] += av.y * bv.y; acc[1][2] += av.y * bv.z; acc[1][3] += av.y * bv.w;
      acc[2][0] += av.z * bv.x; acc[2][1] += av.z * bv.y; acc[2][2] += av.z * bv.z; acc[2][3] += av.z * bv.w;
      acc[3][0] += av.w * bv.x; acc[3][1] += av.w * bv.y; acc[3][2] += av.w * bv.z; acc[3][3] += av.w * bv.w;
    }
    __syncthreads();
  }
#pragma unroll
  for (int i = 0; i < 4; ++i) {
    int m = m0 + ty * 4 + i;
    if (m < M) {
      int n = n0 + tx * 4;
      if (MODE == 0) {
        int bb = m >= LQ;
        float invb = aux1[5 + bb * 2];
        float4 cv = *(const float4*)&aux2[(bb << 8) + n];
        float4 o;
        o.x = acc[i][0] * invb + cv.x; o.y = acc[i][1] * invb + cv.y;
        o.z = acc[i][2] * invb + cv.z; o.w = acc[i][3] * invb + cv.w;
        *(float4*)&C[(size_t)m * 256 + n] = o;
      } else {  // MODE 3
        int bb = m >= LQ;
        int l = m - bb * LQ;
        float4 o;
#pragma unroll
        for (int j = 0; j < 4; ++j) {
          int nc = n + j;
          float v = fmaxf(acc[i][j] + aux1[nc], 0.f);
          float mwv = aux2[(size_t)((bb << 8) + nc) * LQ + l];
          ((float*)&o)[j] = v * mwv;
        }
        *(float4*)&C[(size_t)m * 256 + n] = o;
      }
    }
  }
}

// -------------------- MFMA bf16 GEMM #1: in-proj --------------------
__global__ __launch_bounds__(256) void k_mm1(const ushort* __restrict__ Ah,
                                             const ushort* __restrict__ Bh,
                                             float* __restrict__ C) {
  int lane = threadIdx.x & 63, wid = threadIdx.x >> 6;
  int mbase = blockIdx.x * 128 + (wid >> 1) * 64;
  int nbase = blockIdx.y * 128 + (wid & 1) * 64;
  int lm = lane & 15, lk = (lane >> 4) * 8;
  f32x4 acc[4][4] = {};
  for (int ks = 0; ks < 256; ks += 32) {
    bf16x8 a[4], b[4];
#pragma unroll
    for (int mi = 0; mi < 4; ++mi) {
      int row = mbase + mi * 16 + lm;
      row = row < BLQ ? row : BLQ - 1;
      a[mi] = *(const bf16x8*)&Ah[(size_t)row * 256 + ks + lk];
    }
#pragma unroll
    for (int ni = 0; ni < 4; ++ni) {
      int nr = nbase + ni * 16 + lm;
      b[ni] = *(const bf16x8*)&Bh[(size_t)nr * 256 + ks + lk];
    }
#pragma unroll
    for (int mi = 0; mi < 4; ++mi)
#pragma unroll
      for (int ni = 0; ni < 4; ++ni)
        acc[mi][ni] = __builtin_amdgcn_mfma_f32_16x16x32_bf16(a[mi], b[ni], acc[mi][ni], 0, 0, 0);
  }
  int rbase = (lane >> 4) * 4;
#pragma unroll
  for (int mi = 0; mi < 4; ++mi)
#pragma unroll
    for (int r = 0; r < 4; ++r) {
      int m = mbase + mi * 16 + rbase + r;
      if (m < BLQ) {
#pragma unroll
        for (int ni = 0; ni < 4; ++ni)
          C[(size_t)m * 2048 + nbase + ni * 16 + lm] = acc[mi][ni][r];
      }
    }
}

// -------------------- MFMA bf16 GEMM #2: out-proj (accumulate into x) --------------------
__global__ __launch_bounds__(256) void k_mm2(const ushort* __restrict__ Ah,
                                             const ushort* __restrict__ Bh,
                                             float* __restrict__ C) {
  int lane = threadIdx.x & 63, wid = threadIdx.x >> 6;
  int mbase = blockIdx.x * 128 + (wid >> 1) * 64;
  int nbase = blockIdx.y * 128 + (wid & 1) * 64;
  int lm = lane & 15, lk = (lane >> 4) * 8;
  f32x4 acc[4][4] = {};
  for (int ks = 0; ks < 1024; ks += 32) {
    int dir = ks >> 9;
    int di = (ks & 511) + lk;
    const ushort* Ab = Ah + (size_t)dir * BLQ * 512 + di;
    const ushort* Bb = Bh + (size_t)dir * 131072 + di;
    bf16x8 a[4], b[4];
#pragma unroll
    for (int mi = 0; mi < 4; ++mi) {
      int row = mbase + mi * 16 + lm;
      row = row < BLQ ? row : BLQ - 1;
      a[mi] = *(const bf16x8*)&Ab[(size_t)row * 512];
    }
#pragma unroll
    for (int ni = 0; ni < 4; ++ni) {
      int nr = nbase + ni * 16 + lm;
      b[ni] = *(const bf16x8*)&Bb[(size_t)nr * 512];
    }
#pragma unroll
    for (int mi = 0; mi < 4; ++mi)
#pragma unroll
      for (int ni = 0; ni < 4; ++ni)
        acc[mi][ni] = __builtin_amdgcn_mfma_f32_16x16x32_bf16(a[mi], b[ni], acc[mi][ni], 0, 0, 0);
  }
  int rbase = (lane >> 4) * 4;
#pragma unroll
  for (int mi = 0; mi < 4; ++mi)
#pragma unroll
    for (int r = 0; r < 4; ++r) {
      int m = mbase + mi * 16 + rbase + r;
      if (m < BLQ) {
#pragma unroll
        for (int ni = 0; ni < 4; ++ni) {
          size_t idx = (size_t)m * 256 + nbase + ni * 16 + lm;
          C[idx] += acc[mi][ni][r];
        }
      }
    }
}

// -------------------- xproj GEMM with fused depthwise conv + silu (writes xc too) ----
// per dir (blockIdx.z): xdbl[bl][48] = silu(conv(xz_xi)+cb) @ xproj_w^T ; xc materialized
__global__ __launch_bounds__(256) void k_xproj(const float* __restrict__ xz,
                                               const float* __restrict__ cwAll,
                                               const float* __restrict__ cbAll,
                                               const float* __restrict__ Bw,
                                               float* __restrict__ xc,
                                               float* __restrict__ xdbl,
                                               int blk) {
  int dir = blockIdx.z;
  int w = blk * 2 + dir;
  const float* Bwp = Bw + (size_t)dir * 48 * 512;
  float* xcp = xc + (size_t)dir * BLQ * 512;
  float* xdp = xdbl + (size_t)dir * BLQ * 48;
  __shared__ float As[16][68];
  __shared__ float Bs[16][68];
  int t = threadIdx.x;
  int m0 = blockIdx.x * 64;
  int tx = t & 15, ty = t >> 4;
  float acc[4][4] = {};
  for (int kk = 0; kk < 512; kk += 16) {
    // ---- A tile: conv + silu fused, store to LDS + xc ----
    {
      int m_ = t >> 2, k4q = (t & 3) * 4;
      int m = m0 + m_;
      float4 v = make_float4(0.f, 0.f, 0.f, 0.f);
      if (m < BLQ) {
        int bb = m >= LQ;
        int l = m - bb * LQ;
        int d = kk + k4q;
        float4 cw0 = *(const float4*)&cwAll[(size_t)(w * 512 + d + 0) * 4];
        float4 cw1 = *(const float4*)&cwAll[(size_t)(w * 512 + d + 1) * 4];
        float4 cw2 = *(const float4*)&cwAll[(size_t)(w * 512 + d + 2) * 4];
        float4 cw3 = *(const float4*)&cwAll[(size_t)(w * 512 + d + 3) * 4];
        float4 a = *(const float4*)&cbAll[w * 512 + d];
#pragma unroll
        for (int j = 0; j < 4; ++j) {
          int ls = dir ? (l + 3 - j) : (l - 3 + j);
          if (ls >= 0 && ls < LQ) {
            float4 xv = *(const float4*)&xz[(size_t)(bb * LQ + ls) * 2048 + dir * 1024 + d];
            a.x += xv.x * ((const float*)&cw0)[j];
            a.y += xv.y * ((const float*)&cw1)[j];
            a.z += xv.z * ((const float*)&cw2)[j];
            a.w += xv.w * ((const float*)&cw3)[j];
          }
        }
        v.x = a.x / (1.f + __expf(-a.x));
        v.y = a.y / (1.f + __expf(-a.y));
        v.z = a.z / (1.f + __expf(-a.z));
        v.w = a.w / (1.f + __expf(-a.w));
        *(float4*)&xcp[(size_t)m * 512 + d] = v;
      }
      As[k4q + 0][m_] = v.x; As[k4q + 1][m_] = v.y;
      As[k4q + 2][m_] = v.z; As[k4q + 3][m_] = v.w;
    }
    // ---- B tile ----
    {
      int n_ = t >> 2, k4 = (t & 3) * 4;
      float4 v = make_float4(0.f, 0.f, 0.f, 0.f);
      if (n_ < 48) v = *(const float4*)&Bwp[(size_t)n_ * 512 + kk + k4];
      Bs[k4 + 0][n_] = v.x; Bs[k4 + 1][n_] = v.y;
      Bs[k4 + 2][n_] = v.z; Bs[k4 + 3][n_] = v.w;
    }
    __syncthreads();
#pragma unroll
    for (int k = 0; k < 16; ++k) {
      float4 av = *(const float4*)&As[k][ty * 4];
      float4 bv = *(const float4*)&Bs[k][tx * 4];
      acc[0][0] += av.x * bv.x; acc[0][1] += av.x * bv.y; acc[0][2] += av.x * bv.z; acc[0][3] += av.x * bv.w;
      acc[1][0] += av.y * bv.x; acc[1][1] += av.y * bv.y; acc[1][2] += av.y * bv.z; acc[1][3] += av.y * bv.w;
      acc[2][0] += av.z * bv.x; acc[2][1] += av.z * bv.y; acc[2][2] += av.z * bv.z; acc[2][3] += av.z * bv.w;
      acc[3][0] += av.w * bv.x; acc[3][1] += av.w * bv.y; acc[3][2] += av.w * bv.z; acc[3][3] += av.w * bv.w;
    }
    __syncthreads();
  }
#pragma unroll
  for (int i = 0; i < 4; ++i) {
    int m = m0 + ty * 4 + i;
    if (m < BLQ) {
      int n = tx * 4;
#pragma unroll
      for (int j = 0; j < 4; ++j) {
        int nc = n + j;
        if (nc < 48) xdp[(size_t)m * 48 + nc] = acc[i][j];
      }
    }
  }
}

// ==================== chunked selective scan, fused dt, two kernels ====================
__global__ __launch_bounds__(256) void k_scanA(const float* __restrict__ xc,
                                               const float* __restrict__ xdbl,
                                               const float* __restrict__ dtwt,
                                               const float* __restrict__ dtb,
                                               const float* __restrict__ alog,
                                               float* __restrict__ prod,
                                               float* __restrict__ loc, int blk) {
  __shared__ float s_dx[64 * 17 * 2];
  __shared__ float s_bc[64 * 16 * 2];
  int t = threadIdx.x;
  int bid = blockIdx.x;
  int cpair = bid & 7;
  int wb = bid >> 3;
  int dg = wb & 31;
  int b = (wb >> 5) & 1;
  int dir = wb >> 6;
  int dloc = t >> 4, s = t & 15;
  int d0 = dg * 16;
  int d = d0 + dloc;
  int w = blk * 2 + dir;
  int b999 = b * LQ;
  float a2 = -__expf(alog[(size_t)(w * 512 + d) * 16 + s]) * 1.44269504f;
  const float* xcp = xc + (size_t)dir * BLQ * 512;
  const float* xdp = xdbl + (size_t)dir * BLQ * 48;
  const float* Wt = dtwt + (w << 13);
  float dtbv_ = dtb[w * 512 + d0 + (t & 15)];  // note: staging uses dl = t&15
  size_t wbase = (size_t)wb * 4096;
  int c0 = cpair * 2;

  auto stage = [&](int cc) {
    int j16 = t >> 4, dl = t & 15;
#pragma unroll
    for (int it = 0; it < 4; ++it) {
      int j = it * 16 + j16;
      int tg = cc * 64 + j;
      float dtv = 0.f, xv = 0.f;
      if (tg < LQ) {
        int l = dir ? (LQ - 1 - tg) : tg;
        size_t bl = (size_t)(b999 + l);
        xv = xcp[bl * 512 + d0 + dl];
        const float* xd = xdp + bl * 48;
        float acc = dtbv_;
#pragma unroll
        for (int q = 0; q < 16; ++q) acc += xd[q] * Wt[q * 512 + d0 + dl];
        dtv = softplusf(acc);
      }
      s_dx[(j * 17 + dl) * 2] = dtv;
      s_dx[(j * 17 + dl) * 2 + 1] = xv;
    }
    int j8 = t >> 5, idx = t & 31;
#pragma unroll
    for (int it = 0; it < 8; ++it) {
      int j = it * 8 + j8;
      int tg = cc * 64 + j;
      float v = 0.f;
      if (tg < LQ) {
        int l = dir ? (LQ - 1 - tg) : tg;
        v = xdp[(size_t)(b999 + l) * 48 + 16 + idx];
      }
      int ss = idx & 15, isC = idx >> 4;
      s_bc[(j * 16 + ss) * 2 + isC] = v;
    }
  };

#pragma unroll
  for (int ci = 0; ci < 2; ++ci) {
    int cc = c0 + ci;
    stage(cc);
    __syncthreads();
    float h = 0.f, pr = 1.f;
#pragma unroll 16
    for (int j = 0; j < 64; ++j) {
      float2 dx = *(float2*)&s_dx[(j * 17 + dloc) * 2];
      float Bv = s_bc[(j * 16 + s) * 2];
      float dA = exp2f(dx.x * a2);
      pr *= dA;
      h = dA * h + dx.x * dx.y * Bv;
    }
    prod[wbase + cc * 256 + t] = pr;
    loc[wbase + cc * 256 + t] = h;
    __syncthreads();
  }
}

__global__ __launch_bounds__(256) void k_scanC(const float* __restrict__ xc,
                                               const float* __restrict__ xdbl,
                                               const float* __restrict__ dtwt,
                                               const float* __restrict__ dtb,
                                               const float* __restrict__ xz,
                                               const float* __restrict__ alog,
                                               const float* __restrict__ dmat,
                                               const float* __restrict__ prod,
                                               const float* __restrict__ loc,
                                               ushort* __restrict__ gh, int blk) {
  __shared__ float s_dx[64 * 17 * 2];
  __shared__ float s_bc[64 * 16 * 2];
  int t = threadIdx.x;
  int bid = blockIdx.x;
  int cpair = bid & 7;
  int wb = bid >> 3;
  int dg = wb & 31;
  int b = (wb >> 5) & 1;
  int dir = wb >> 6;
  int dloc = t >> 4, s = t & 15;
  int d0 = dg * 16;
  int d = d0 + dloc;
  int w = blk * 2 + dir;
  int b999 = b * LQ;
  float a2 = -__expf(alog[(size_t)(w * 512 + d) * 16 + s]) * 1.44269504f;
  float Dd = dmat[w * 512 + d];
  const float* xcp = xc + (size_t)dir * BLQ * 512;
  const float* xdp = xdbl + (size_t)dir * BLQ * 48;
  const float* Wt = dtwt + (w << 13);
  float dtbv_ = dtb[w * 512 + d0 + (t & 15)];
  const float* zp = xz + dir * 1024 + 512 + d;
  ushort* gp = gh + (size_t)dir * BLQ * 512;
  size_t wbase = (size_t)wb * 4096;
  int c0 = cpair * 2;

  auto stage = [&](int cc) {
    int j16 = t >> 4, dl = t & 15;
#pragma unroll
    for (int it = 0; it < 4; ++it) {
      int j = it * 16 + j16;
      int tg = cc * 64 + j;
      float dtv = 0.f, xv = 0.f;
      if (tg < LQ) {
        int l = dir ? (LQ - 1 - tg) : tg;
        size_t bl = (size_t)(b999 + l);
        xv = xcp[bl * 512 + d0 + dl];
        const float* xd = xdp + bl * 48;
        float acc = dtbv_;
#pragma unroll
        for (int q = 0; q < 16; ++q) acc += xd[q] * Wt[q * 512 + d0 + dl];
        dtv = softplusf(acc);
      }
      s_dx[(j * 17 + dl) * 2] = dtv;
      s_dx[(j * 17 + dl) * 2 + 1] = xv;
    }
    int j8 = t >> 5, idx = t & 31;
#pragma unroll
    for (int it = 0; it < 8; ++it) {
      int j = it * 8 + j8;
      int tg = cc * 64 + j;
      float v = 0.f;
      if (tg < LQ) {
        int l = dir ? (LQ - 1 - tg) : tg;
        v = xdp[(size_t)(b999 + l) * 48 + 16 + idx];
      }
      int ss = idx & 15, isC = idx >> 4;
      s_bc[(j * 16 + ss) * 2 + isC] = v;
    }
  };

  // chain over 16 chunks
  float hs0 = 0.f, hs1 = 0.f;
  {
    float h = 0.f;
#pragma unroll
    for (int ccc = 0; ccc < NCHK; ++ccc) {
      if (ccc == c0) hs0 = h;
      if (ccc == c0 + 1) hs1 = h;
      float prv = prod[wbase + ccc * 256 + t];
      float lov = loc[wbase + ccc * 256 + t];
      h = prv * h + lov;
    }
  }

  auto zload = [&](int cc, int j0n) -> float {
    int tg = cc * 64 + j0n + s;
    if (j0n < 64 && tg < LQ) {
      int l = dir ? (LQ - 1 - tg) : tg;
      return zp[(size_t)(b999 + l) * 2048];
    }
    return 0.f;
  };

#pragma unroll
  for (int ci = 0; ci < 2; ++ci) {
    int cc = c0 + ci;
    stage(cc);
    __syncthreads();
    float h = ci ? hs1 : hs0;
    float keepP = 0.f;
    float zq = zload(cc, 0);
    for (int j0 = 0; j0 < 64; j0 += 16) {
#pragma unroll
      for (int jj = 0; jj < 16; ++jj) {
        int j = j0 + jj;
        float2 dx = *(float2*)&s_dx[(j * 17 + dloc) * 2];
        float2 bc = *(float2*)&s_bc[(j * 16 + s) * 2];
        float dA = exp2f(dx.x * a2);
        h = dA * h + dx.x * dx.y * bc.x;
        float p = h * bc.y;
        p += __shfl_xor(p, 1, 16);
        p += __shfl_xor(p, 2, 16);
        p += __shfl_xor(p, 4, 16);
        p += __shfl_xor(p, 8, 16);
        if (jj == s) keepP = p;
      }
      int tg = cc * 64 + j0 + s;
      float xv = s_dx[((j0 + s) * 17 + dloc) * 2 + 1];
      float zv = zq;
      zq = zload(cc, j0 + 16);
      float sig = 1.f / (1.f + __expf(-zv));
      float y = (keepP + xv * Dd) * (zv * sig);
      if (tg < LQ) {
        int l = dir ? (LQ - 1 - tg) : tg;
        gp[(size_t)(b999 + l) * 512 + d] = f2bf(y);
      }
    }
    __syncthreads();
  }
}

// -------------------- decoder as GEMM + combine --------------------
__global__ __launch_bounds__(256) void k_zg(const float* __restrict__ Mt,
                                            const float* __restrict__ dw,
                                            float* __restrict__ Z) {
  __shared__ float sm[16][260];
  __shared__ float sw[256][16];
  int t = threadIdx.x;
  int b = blockIdx.x >= 63;
  int r0 = (blockIdx.x - b * 63) * 16;
#pragma unroll
  for (int it = 0; it < 16; ++it) {
    int e = it * 256 + t;
    int r = e >> 8, c = e & 255;
    int l = r0 + r;
    sm[r][c] = (l < LQ) ? Mt[(size_t)(b * LQ + l) * 256 + c] : 0.f;
    sw[e >> 4][e & 15] = dw[e];
  }
  __syncthreads();
  int lrow = t >> 4, j = t & 15;
  float acc = 0.f;
#pragma unroll 8
  for (int n = 0; n < 256; ++n) acc += sm[lrow][n] * sw[n][j];
  int l = r0 + lrow;
  Z[(size_t)(b * 1008 + l) * 16 + j] = acc;
}

__global__ __launch_bounds__(256) void k_comb(const float* __restrict__ Z,
                                              float* __restrict__ out) {
  int idx = blockIdx.x * 256 + threadIdx.x;
  if (idx >= 16000) return;
  int b = idx >= 8000;
  int tt = idx - b * 8000;
  int l0 = tt >> 3, j0 = tt & 7;
  float v = 0.f;
  if (l0 <= LQ - 1) v += Z[(size_t)(b * 1008 + l0) * 16 + j0];
  if (l0 >= 1) v += Z[(size_t)(b * 1008 + l0 - 1) * 16 + j0 + 8];
  out[idx] = v;
}

// ==================== launch ====================
extern "C" void kernel_launch(void* const* d_in, const int* in_sizes, int n_in,
                              void* d_out, int out_size, void* d_ws, size_t ws_size,
                              hipStream_t stream) {
  const float* mixture = (const float*)d_in[0];
  const float* enc_w = (const float*)d_in[1];
  const float* dec_w = (const float*)d_in[2];
  const float* gn_w = (const float*)d_in[3];
  const float* gn_b = (const float*)d_in[4];
  const float* bot_w = (const float*)d_in[5];
  const float* bot_b = (const float*)d_in[6];
  const float* blk_norm_w = (const float*)d_in[7];
  const float* in_w = (const float*)d_in[8];
  const float* conv_w = (const float*)d_in[9];
  const float* conv_b = (const float*)d_in[10];
  const float* xproj_w = (const float*)d_in[11];
  const float* dt_w = (const float*)d_in[12];
  const float* dt_b = (const float*)d_in[13];
  const float* A_log = (const float*)d_in[14];
  const float* Dmat = (const float*)d_in[15];
  const float* out_w = (const float*)d_in[16];
  const float* normf_w = (const float*)d_in[17];
  const float* mask_w = (const float*)d_in[18];
  const float* mask_b = (const float*)d_in[19];
  float* outp = (float*)d_out;

  float* W = (float*)d_ws;
  size_t off = 0;
  auto alloc = [&](size_t n) {
    float* p = W + off;
    off += (n + 255) & ~(size_t)255;
    return p;
  };
  float* stats = alloc(8);
  float* pp = alloc(4096);            // per-block groupnorm partials
  float* w2 = alloc(65536);
  float* cc = alloc(512);
  float* mw = alloc(511488);          // [b][n][l]
  float* x = alloc(511488);           // [bl][256]
  float* xn = alloc(511488);          // fp32 (final rms only)
  float* xzb = alloc(4091904);        // [bl][2048]
  float* xcb = alloc(2045952);        // [dir][bl][512]
  float* xdblb = alloc(191808);       // [dir][bl][48]
  float* maskedb = alloc(511488);     // masked_t [bl][256]
  float* prodb = alloc(524288);
  float* locb = alloc(524288);
  float* zbuf = alloc(32256);         // [2][1008][16]
  float* dtwt = alloc(131072);        // transposed dt weights [w][q][512]
  ushort* xnh = (ushort*)alloc(255744);
  ushort* ghb = (ushort*)alloc(1022976);
  ushort* inwh = (ushort*)alloc(2097152);
  ushort* outwh = (ushort*)alloc(1048576);

  k_quant<<<16384, 256, 0, stream>>>(in_w, out_w, dt_w, inwh, outwh, dtwt);
  k_enc<<<1998, 256, 0, stream>>>(mixture, enc_w, mw, pp);
  k_stats<<<2, 256, 0, stream>>>(pp, stats);
  k_prep<<<256, 256, 0, stream>>>(bot_w, gn_w, gn_b, bot_b, stats, w2, cc);
  gemm64<0><<<dim3(32, 4, 1), 256, 0, stream>>>(mw, w2, x, stats, cc, BLQ, 256);

  for (int i = 0; i < 8; ++i) {
    k_rms<true><<<500, 256, 0, stream>>>(x, blk_norm_w + i * 256, nullptr, xnh);
    k_mm1<<<dim3(16, 16), 256, 0, stream>>>(xnh, inwh + (size_t)i * 524288, xzb);
    k_xproj<<<dim3(32, 1, 2), 256, 0, stream>>>(
        xzb, conv_w, conv_b, xproj_w + (size_t)i * 2 * 48 * 512, xcb, xdblb, i);
    k_scanA<<<1024, 256, 0, stream>>>(xcb, xdblb, dtwt, dt_b, A_log, prodb, locb, i);
    k_scanC<<<1024, 256, 0, stream>>>(xcb, xdblb, dtwt, dt_b, xzb, A_log, Dmat,
                                      prodb, locb, ghb, i);
    k_mm2<<<dim3(16, 2), 256, 0, stream>>>(ghb, outwh + (size_t)i * 262144, x);
  }

  k_rms<false><<<500, 256, 0, stream>>>(x, normf_w, xn, nullptr);
  gemm64<3><<<dim3(32, 4, 1), 256, 0, stream>>>(xn, mask_w, maskedb, mask_b, mw, BLQ, 256);
  k_zg<<<126, 256, 0, stream>>>(maskedb, dec_w, zbuf);
  k_comb<<<63, 256, 0, stream>>>(zbuf, outp);
}

// Round 11
// 1397.030 us; speedup vs baseline: 1.2812x; 1.2812x over previous
//
#include <hip/hip_runtime.h>
#include <cstdint>
#include <cmath>

// Shapes (fixed by the problem)
#define LQ   999      // conv output length (8000-16)/8+1
#define BLQ  1998     // BATCH * LQ
#define NCH  256      // encoder channels
#define NLTOT 255744  // NCH*LQ (per batch)
#define NCHK 16       // scan chunks per sequence
#define CHL  64       // chunk length (16*64=1024 >= 999)

typedef __attribute__((ext_vector_type(8))) short bf16x8;
typedef __attribute__((ext_vector_type(4))) float f32x4;

__device__ inline ushort f2bf(float f) {
  uint32_t u = __float_as_uint(f);
  u += 0x7fff + ((u >> 16) & 1);
  return (ushort)(u >> 16);
}

// -------------------- one-time weight quantize / transpose --------------------
__global__ __launch_bounds__(256) void k_quant(const float* __restrict__ inw,
                                               const float* __restrict__ outw,
                                               const float* __restrict__ dtw,
                                               ushort* __restrict__ inwh,
                                               ushort* __restrict__ outwh,
                                               float* __restrict__ dtwt) {
  int i = blockIdx.x * 256 + threadIdx.x;
  if (i < 4194304) inwh[i] = f2bf(inw[i]);
  if (i < 2097152) outwh[i] = f2bf(outw[i]);
  if (i < 131072) {
    int w = i >> 13, d = (i >> 4) & 511, q = i & 15;
    dtwt[(w << 13) + q * 512 + d] = dtw[i];
  }
}

// -------------------- encoder conv + relu + per-block groupnorm partials --------------------
__global__ __launch_bounds__(256) void k_enc(const float* __restrict__ mix,
                                             const float* __restrict__ ew,
                                             float* __restrict__ mw,
                                             float* __restrict__ pp) {
  int t = threadIdx.x;
  int b = blockIdx.x >= LQ;
  int rem = (blockIdx.x - b * LQ) * 256 + t;
  int n = rem / LQ;
  int l = rem - n * LQ;
  const float* mp = mix + b * 8000 + l * 8;
  const float* wp = ew + n * 16;
  float acc = 0.f;
#pragma unroll
  for (int k = 0; k < 16; ++k) acc += mp[k] * wp[k];
  float v = fmaxf(acc, 0.f);
  mw[(b * NCH + n) * LQ + l] = v;
  float s1 = v, s2 = v * v;
#pragma unroll
  for (int off = 32; off >= 1; off >>= 1) {
    s1 += __shfl_xor(s1, off, 64);
    s2 += __shfl_xor(s2, off, 64);
  }
  __shared__ float r1[4], r2[4];
  int wv = t >> 6, lane = t & 63;
  if (lane == 0) { r1[wv] = s1; r2[wv] = s2; }
  __syncthreads();
  if (t == 0) {
    pp[blockIdx.x * 2 + 0] = r1[0] + r1[1] + r1[2] + r1[3];
    pp[blockIdx.x * 2 + 1] = r2[0] + r2[1] + r2[2] + r2[3];
  }
}

// reduce per-block partials -> mean / invstd per batch (grid = 2 blocks)
__global__ __launch_bounds__(256) void k_stats(const float* __restrict__ pp,
                                               float* __restrict__ stats) {
  int t = threadIdx.x;
  int b = blockIdx.x;
  float s1 = 0.f, s2 = 0.f;
  for (int i = t; i < LQ; i += 256) {
    s1 += pp[(b * LQ + i) * 2 + 0];
    s2 += pp[(b * LQ + i) * 2 + 1];
  }
#pragma unroll
  for (int off = 32; off >= 1; off >>= 1) {
    s1 += __shfl_xor(s1, off, 64);
    s2 += __shfl_xor(s2, off, 64);
  }
  __shared__ float r1[4], r2[4];
  int wv = t >> 6, lane = t & 63;
  if (lane == 0) { r1[wv] = s1; r2[wv] = s2; }
  __syncthreads();
  if (t == 0) {
    float S1 = r1[0] + r1[1] + r1[2] + r1[3];
    float S2 = r2[0] + r2[1] + r2[2] + r2[3];
    float mu = S1 / (float)NLTOT;
    float var = S2 / (float)NLTOT - mu * mu;
    stats[4 + b * 2] = mu;
    stats[5 + b * 2] = 1.f / sqrtf(var + 1e-5f);
  }
}

__global__ __launch_bounds__(256) void k_prep(const float* __restrict__ bw,
                                              const float* __restrict__ gw,
                                              const float* __restrict__ gb,
                                              const float* __restrict__ bb,
                                              const float* __restrict__ stats,
                                              float* __restrict__ w2,
                                              float* __restrict__ cc) {
  int o = blockIdx.x, n = threadIdx.x;
  float bwv = bw[o * 256 + n];
  float w2v = bwv * gw[n];
  w2[o * 256 + n] = w2v;
  float s1 = bwv * gb[n], s2 = w2v;
#pragma unroll
  for (int off = 32; off >= 1; off >>= 1) {
    s1 += __shfl_xor(s1, off, 64);
    s2 += __shfl_xor(s2, off, 64);
  }
  __shared__ float r1[4], r2[4];
  int wv = n >> 6, lane = n & 63;
  if (lane == 0) { r1[wv] = s1; r2[wv] = s2; }
  __syncthreads();
  if (n == 0) {
    float a1 = r1[0] + r1[1] + r1[2] + r1[3];
    float a2 = r2[0] + r2[1] + r2[2] + r2[3];
    for (int b = 0; b < 2; ++b)
      cc[b * 256 + o] = bb[o] + a1 - stats[4 + b * 2] * stats[5 + b * 2] * a2;
  }
}

// -------------------- rmsnorm over last dim (256); BF=true writes bf16 --------------------
template <bool BF>
__global__ __launch_bounds__(256) void k_rms(const float* __restrict__ x,
                                             const float* __restrict__ w,
                                             float* __restrict__ out,
                                             ushort* __restrict__ outh) {
  int t = threadIdx.x;
  int row = blockIdx.x * 4 + (t >> 6);
  int lane = t & 63;
  if (row >= BLQ) return;
  float4 v = *(const float4*)&x[row * 256 + lane * 4];
  float ss = v.x * v.x + v.y * v.y + v.z * v.z + v.w * v.w;
#pragma unroll
  for (int off = 32; off >= 1; off >>= 1) ss += __shfl_xor(ss, off, 64);
  float r = 1.f / sqrtf(ss * (1.f / 256.f) + 1e-5f);
  float4 wv = *(const float4*)&w[lane * 4];
  float4 o;
  o.x = v.x * wv.x * r; o.y = v.y * wv.y * r;
  o.z = v.z * wv.z * r; o.w = v.w * wv.w * r;
  if (BF) {
    ushort4 oh = {f2bf(o.x), f2bf(o.y), f2bf(o.z), f2bf(o.w)};
    *(ushort4*)&outh[row * 256 + lane * 4] = oh;
  } else {
    *(float4*)&out[row * 256 + lane * 4] = o;
  }
}

// -------------------- generic 64x64 tiled fp32 GEMM, C = A * B^T --------------------
// MODE 0: bottleneck  A=mw (col-gather + norm fold), B=w2, C=x (256)
// MODE 3: masks       A=xn (row-major), B=mask_w, epilogue relu*mw -> masked_t[bl][256]
template <int MODE>
__global__ __launch_bounds__(256) void gemm64(const float* __restrict__ A,
                                              const float* __restrict__ Bw,
                                              float* __restrict__ C,
                                              const float* __restrict__ aux1,
                                              const float* __restrict__ aux2,
                                              int M, int K) {
  __shared__ float As[16][68];
  __shared__ float Bs[16][68];
  int t = threadIdx.x;
  int m0 = blockIdx.x * 64, n0 = blockIdx.y * 64;
  int tx = t & 15, ty = t >> 4;
  float acc[4][4] = {};
  for (int kk = 0; kk < K; kk += 16) {
    if (MODE == 0) {
#pragma unroll
      for (int j = 0; j < 4; ++j) {
        int e = t + 256 * j;
        int m_ = e & 63, k_ = e >> 6;
        int m = m0 + m_;
        float v = 0.f;
        if (m < M) {
          int bb = m >= LQ;
          int l = m - bb * LQ;
          v = A[(size_t)((bb << 8) + kk + k_) * LQ + l];
        }
        As[k_][m_] = v;
      }
    } else {
      int m_ = t >> 2, k4 = (t & 3) * 4;
      int m = m0 + m_;
      float4 v = make_float4(0.f, 0.f, 0.f, 0.f);
      if (m < M) v = *(const float4*)&A[(size_t)m * K + kk + k4];
      As[k4 + 0][m_] = v.x; As[k4 + 1][m_] = v.y;
      As[k4 + 2][m_] = v.z; As[k4 + 3][m_] = v.w;
    }
    {
      int n_ = t >> 2, k4 = (t & 3) * 4;
      int n = n0 + n_;
      float4 v = *(const float4*)&Bw[(size_t)n * K + kk + k4];
      Bs[k4 + 0][n_] = v.x; Bs[k4 + 1][n_] = v.y;
      Bs[k4 + 2][n_] = v.z; Bs[k4 + 3][n_] = v.w;
    }
    __syncthreads();
#pragma unroll
    for (int k = 0; k < 16; ++k) {
      float4 av = *(const float4*)&As[k][ty * 4];
      float4 bv = *(const float4*)&Bs[k][tx * 4];
      acc[0][0] += av.x * bv.x; acc[0][1] += av.x * bv.y; acc[0][2] += av.x * bv.z; acc[0][3] += av.x * bv.w;
      acc[1][0] += av.y * bv.x; acc[1][1] += av.y * bv.y; acc[1][2] += av.y * bv.z; acc[1][3] += av.y * bv.w;
      acc[2][0] += av.z * bv.x; acc[2][1] += av.z * bv.y; acc[2][2] += av.z * bv.z; acc[2][3] += av.z * bv.w;
      acc[3][0] += av.w * bv.x; acc[3][1] += av.w * bv.y; acc[3][2] += av.w * bv.z; acc[3][3] += av.w * bv.w;
    }
    __syncthreads();
  }
#pragma unroll
  for (int i = 0; i < 4; ++i) {
    int m = m0 + ty * 4 + i;
    if (m < M) {
      int n = n0 + tx * 4;
      if (MODE == 0) {
        int bb = m >= LQ;
        float invb = aux1[5 + bb * 2];
        float4 cv = *(const float4*)&aux2[(bb << 8) + n];
        float4 o;
        o.x = acc[i][0] * invb + cv.x; o.y = acc[i][1] * invb + cv.y;
        o.z = acc[i][2] * invb + cv.z; o.w = acc[i][3] * invb + cv.w;
        *(float4*)&C[(size_t)m * 256 + n] = o;
      } else {  // MODE 3
        int bb = m >= LQ;
        int l = m - bb * LQ;
        float4 o;
#pragma unroll
        for (int j = 0; j < 4; ++j) {
          int nc = n + j;
          float v = fmaxf(acc[i][j] + aux1[nc], 0.f);
          float mwv = aux2[(size_t)((bb << 8) + nc) * LQ + l];
          ((float*)&o)[j] = v * mwv;
        }
        *(float4*)&C[(size_t)m * 256 + n] = o;
      }
    }
  }
}

// -------------------- xproj GEMM, splitK x4 over K=512 (atomicAdd epilogue) ----------
// grid (32, 4, 2): x = m-tile (64 rows), y = k-slice (128), z = dir
__global__ __launch_bounds__(256) void k_xprojK(const float* __restrict__ A,
                                                const float* __restrict__ Bw,
                                                float* __restrict__ C,
                                                int blk) {
  int dir = blockIdx.z;
  const float* Ap = A + (size_t)dir * BLQ * 512;
  const float* Bwp = Bw + (size_t)dir * 48 * 512;
  float* Cp = C + (size_t)dir * BLQ * 48;
  __shared__ float As[16][68];
  __shared__ float Bs[16][68];
  int t = threadIdx.x;
  int m0 = blockIdx.x * 64;
  int k0 = blockIdx.y * 128;
  int tx = t & 15, ty = t >> 4;
  float acc[4][4] = {};
  for (int kk = k0; kk < k0 + 128; kk += 16) {
    {
      int m_ = t >> 2, k4 = (t & 3) * 4;
      int m = m0 + m_;
      float4 v = make_float4(0.f, 0.f, 0.f, 0.f);
      if (m < BLQ) v = *(const float4*)&Ap[(size_t)m * 512 + kk + k4];
      As[k4 + 0][m_] = v.x; As[k4 + 1][m_] = v.y;
      As[k4 + 2][m_] = v.z; As[k4 + 3][m_] = v.w;
    }
    {
      int n_ = t >> 2, k4 = (t & 3) * 4;
      float4 v = make_float4(0.f, 0.f, 0.f, 0.f);
      if (n_ < 48) v = *(const float4*)&Bwp[(size_t)n_ * 512 + kk + k4];
      Bs[k4 + 0][n_] = v.x; Bs[k4 + 1][n_] = v.y;
      Bs[k4 + 2][n_] = v.z; Bs[k4 + 3][n_] = v.w;
    }
    __syncthreads();
#pragma unroll
    for (int k = 0; k < 16; ++k) {
      float4 av = *(const float4*)&As[k][ty * 4];
      float4 bv = *(const float4*)&Bs[k][tx * 4];
      acc[0][0] += av.x * bv.x; acc[0][1] += av.x * bv.y; acc[0][2] += av.x * bv.z; acc[0][3] += av.x * bv.w;
      acc[1][0] += av.y * bv.x; acc[1][1] += av.y * bv.y; acc[1][2] += av.y * bv.z; acc[1][3] += av.y * bv.w;
      acc[2][0] += av.z * bv.x; acc[2][1] += av.z * bv.y; acc[2][2] += av.z * bv.z; acc[2][3] += av.z * bv.w;
      acc[3][0] += av.w * bv.x; acc[3][1] += av.w * bv.y; acc[3][2] += av.w * bv.z; acc[3][3] += av.w * bv.w;
    }
    __syncthreads();
  }
#pragma unroll
  for (int i = 0; i < 4; ++i) {
    int m = m0 + ty * 4 + i;
    if (m < BLQ) {
      int n = tx * 4;
#pragma unroll
      for (int j = 0; j < 4; ++j) {
        int nc = n + j;
        if (nc < 48) atomicAdd(&Cp[(size_t)m * 48 + nc], acc[i][j]);
      }
    }
  }
}

// -------------------- MFMA bf16 GEMM #1: in-proj --------------------
__global__ __launch_bounds__(256) void k_mm1(const ushort* __restrict__ Ah,
                                             const ushort* __restrict__ Bh,
                                             float* __restrict__ C) {
  int lane = threadIdx.x & 63, wid = threadIdx.x >> 6;
  int mbase = blockIdx.x * 128 + (wid >> 1) * 64;
  int nbase = blockIdx.y * 128 + (wid & 1) * 64;
  int lm = lane & 15, lk = (lane >> 4) * 8;
  f32x4 acc[4][4] = {};
  for (int ks = 0; ks < 256; ks += 32) {
    bf16x8 a[4], b[4];
#pragma unroll
    for (int mi = 0; mi < 4; ++mi) {
      int row = mbase + mi * 16 + lm;
      row = row < BLQ ? row : BLQ - 1;
      a[mi] = *(const bf16x8*)&Ah[(size_t)row * 256 + ks + lk];
    }
#pragma unroll
    for (int ni = 0; ni < 4; ++ni) {
      int nr = nbase + ni * 16 + lm;
      b[ni] = *(const bf16x8*)&Bh[(size_t)nr * 256 + ks + lk];
    }
#pragma unroll
    for (int mi = 0; mi < 4; ++mi)
#pragma unroll
      for (int ni = 0; ni < 4; ++ni)
        acc[mi][ni] = __builtin_amdgcn_mfma_f32_16x16x32_bf16(a[mi], b[ni], acc[mi][ni], 0, 0, 0);
  }
  int rbase = (lane >> 4) * 4;
#pragma unroll
  for (int mi = 0; mi < 4; ++mi)
#pragma unroll
    for (int r = 0; r < 4; ++r) {
      int m = mbase + mi * 16 + rbase + r;
      if (m < BLQ) {
#pragma unroll
        for (int ni = 0; ni < 4; ++ni)
          C[(size_t)m * 2048 + nbase + ni * 16 + lm] = acc[mi][ni][r];
      }
    }
}

// -------------------- MFMA bf16 GEMM #2: out-proj (accumulate into x) --------------------
__global__ __launch_bounds__(256) void k_mm2(const ushort* __restrict__ Ah,
                                             const ushort* __restrict__ Bh,
                                             float* __restrict__ C) {
  int lane = threadIdx.x & 63, wid = threadIdx.x >> 6;
  int mbase = blockIdx.x * 128 + (wid >> 1) * 64;
  int nbase = blockIdx.y * 128 + (wid & 1) * 64;
  int lm = lane & 15, lk = (lane >> 4) * 8;
  f32x4 acc[4][4] = {};
  for (int ks = 0; ks < 1024; ks += 32) {
    int dir = ks >> 9;
    int di = (ks & 511) + lk;
    const ushort* Ab = Ah + (size_t)dir * BLQ * 512 + di;
    const ushort* Bb = Bh + (size_t)dir * 131072 + di;
    bf16x8 a[4], b[4];
#pragma unroll
    for (int mi = 0; mi < 4; ++mi) {
      int row = mbase + mi * 16 + lm;
      row = row < BLQ ? row : BLQ - 1;
      a[mi] = *(const bf16x8*)&Ab[(size_t)row * 512];
    }
#pragma unroll
    for (int ni = 0; ni < 4; ++ni) {
      int nr = nbase + ni * 16 + lm;
      b[ni] = *(const bf16x8*)&Bb[(size_t)nr * 512];
    }
#pragma unroll
    for (int mi = 0; mi < 4; ++mi)
#pragma unroll
      for (int ni = 0; ni < 4; ++ni)
        acc[mi][ni] = __builtin_amdgcn_mfma_f32_16x16x32_bf16(a[mi], b[ni], acc[mi][ni], 0, 0, 0);
  }
  int rbase = (lane >> 4) * 4;
#pragma unroll
  for (int mi = 0; mi < 4; ++mi)
#pragma unroll
    for (int r = 0; r < 4; ++r) {
      int m = mbase + mi * 16 + rbase + r;
      if (m < BLQ) {
#pragma unroll
        for (int ni = 0; ni < 4; ++ni) {
          size_t idx = (size_t)m * 256 + nbase + ni * 16 + lm;
          C[idx] += acc[mi][ni][r];
        }
      }
    }
}

// -------------------- depthwise causal / anti-causal conv + silu --------------------
__global__ __launch_bounds__(256) void k_conv(const float* __restrict__ xz,
                                              const float* __restrict__ cwAll,
                                              const float* __restrict__ cbAll,
                                              float* __restrict__ xc, int blk) {
  int dir = blockIdx.y;
  int flat = blockIdx.x * 256 + threadIdx.x;
  int d = flat & 511, bl = flat >> 9;
  int bb = bl >= LQ;
  int l = bl - bb * LQ;
  int w = blk * 2 + dir;
  const float* cw = cwAll + (size_t)(w * 512 + d) * 4;
  float acc = cbAll[w * 512 + d];
  int zoff = dir * 1024 + d;
#pragma unroll
  for (int j = 0; j < 4; ++j) {
    int ls = (dir == 0) ? (l - 3 + j) : (l + 3 - j);
    if (ls >= 0 && ls < LQ) acc += xz[(size_t)(bb * LQ + ls) * 2048 + zoff] * cw[j];
  }
  float sg = acc / (1.f + __expf(-acc));
  xc[(size_t)(dir * BLQ + bl) * 512 + d] = sg;
}

// -------------------- dt projection (K=16, transposed weights) + softplus --------------------
__global__ __launch_bounds__(256) void k_dt(const float* __restrict__ xdbl,
                                            const float* __restrict__ dtwt,
                                            const float* __restrict__ dtbAll,
                                            float* __restrict__ dtg, int blk) {
  int dir = blockIdx.y;
  int flat = blockIdx.x * 256 + threadIdx.x;
  int d = flat & 511, bl = flat >> 9;
  int w = blk * 2 + dir;
  const float* xd = xdbl + (size_t)(dir * BLQ + bl) * 48;
  const float* Wp = dtwt + (w << 13);
  float acc = dtbAll[w * 512 + d];
#pragma unroll
  for (int q = 0; q < 16; ++q) acc += xd[q] * Wp[q * 512 + d];
  float sp = fmaxf(acc, 0.f) + log1pf(expf(-fabsf(acc)));
  dtg[(size_t)(dir * BLQ + bl) * 512 + d] = sp;
}

// ==================== chunked selective scan, LDS-staged, two kernels ====================
__global__ __launch_bounds__(256) void k_scanA(const float* __restrict__ dtg,
                                               const float* __restrict__ xc,
                                               const float* __restrict__ xdbl,
                                               const float* __restrict__ alog,
                                               float* __restrict__ prod,
                                               float* __restrict__ loc, int blk) {
  __shared__ float s_dx[64 * 17 * 2];
  __shared__ float s_bc[64 * 16 * 2];
  int t = threadIdx.x;
  int bid = blockIdx.x;
  int cpair = bid & 7;
  int wb = bid >> 3;
  int dg = wb & 31;
  int b = (wb >> 5) & 1;
  int dir = wb >> 6;
  int dloc = t >> 4, s = t & 15;
  int d0 = dg * 16;
  int d = d0 + dloc;
  int w = blk * 2 + dir;
  int b999 = b * LQ;
  float a2 = -__expf(alog[(size_t)(w * 512 + d) * 16 + s]) * 1.44269504f;
  const float* dtp = dtg + (size_t)dir * BLQ * 512;
  const float* xcp = xc + (size_t)dir * BLQ * 512;
  const float* xdp = xdbl + (size_t)dir * BLQ * 48;
  size_t wbase = (size_t)wb * 4096;
  int c0 = cpair * 2;

  auto stage = [&](int cc) {
    int j16 = t >> 4, dl = t & 15;
#pragma unroll
    for (int it = 0; it < 4; ++it) {
      int j = it * 16 + j16;
      int tg = cc * 64 + j;
      float dtv = 0.f, xv = 0.f;
      if (tg < LQ) {
        int l = dir ? (LQ - 1 - tg) : tg;
        size_t bl = (size_t)(b999 + l);
        dtv = dtp[bl * 512 + d0 + dl];
        xv = xcp[bl * 512 + d0 + dl];
      }
      s_dx[(j * 17 + dl) * 2] = dtv;
      s_dx[(j * 17 + dl) * 2 + 1] = xv;
    }
    int j8 = t >> 5, idx = t & 31;
#pragma unroll
    for (int it = 0; it < 8; ++it) {
      int j = it * 8 + j8;
      int tg = cc * 64 + j;
      float v = 0.f;
      if (tg < LQ) {
        int l = dir ? (LQ - 1 - tg) : tg;
        v = xdp[(size_t)(b999 + l) * 48 + 16 + idx];
      }
      int ss = idx & 15, isC = idx >> 4;
      s_bc[(j * 16 + ss) * 2 + isC] = v;
    }
  };

#pragma unroll
  for (int ci = 0; ci < 2; ++ci) {
    int cc = c0 + ci;
    stage(cc);
    __syncthreads();
    float h = 0.f, pr = 1.f;
#pragma unroll 16
    for (int j = 0; j < 64; ++j) {
      float2 dx = *(float2*)&s_dx[(j * 17 + dloc) * 2];
      float Bv = s_bc[(j * 16 + s) * 2];
      float dA = exp2f(dx.x * a2);
      pr *= dA;
      h = dA * h + dx.x * dx.y * Bv;
    }
    prod[wbase + cc * 256 + t] = pr;
    loc[wbase + cc * 256 + t] = h;
    __syncthreads();
  }
}

__global__ __launch_bounds__(256) void k_scanC(const float* __restrict__ dtg,
                                               const float* __restrict__ xc,
                                               const float* __restrict__ xdbl,
                                               const float* __restrict__ xz,
                                               const float* __restrict__ alog,
                                               const float* __restrict__ dmat,
                                               const float* __restrict__ prod,
                                               const float* __restrict__ loc,
                                               ushort* __restrict__ gh, int blk) {
  __shared__ float s_dx[64 * 17 * 2];
  __shared__ float s_bc[64 * 16 * 2];
  int t = threadIdx.x;
  int bid = blockIdx.x;
  int cpair = bid & 7;
  int wb = bid >> 3;
  int dg = wb & 31;
  int b = (wb >> 5) & 1;
  int dir = wb >> 6;
  int dloc = t >> 4, s = t & 15;
  int d0 = dg * 16;
  int d = d0 + dloc;
  int w = blk * 2 + dir;
  int b999 = b * LQ;
  float a2 = -__expf(alog[(size_t)(w * 512 + d) * 16 + s]) * 1.44269504f;
  float Dd = dmat[w * 512 + d];
  const float* dtp = dtg + (size_t)dir * BLQ * 512;
  const float* xcp = xc + (size_t)dir * BLQ * 512;
  const float* xdp = xdbl + (size_t)dir * BLQ * 48;
  const float* zp = xz + dir * 1024 + 512 + d;
  ushort* gp = gh + (size_t)dir * BLQ * 512;
  size_t wbase = (size_t)wb * 4096;
  int c0 = cpair * 2;

  auto stage = [&](int cc) {
    int j16 = t >> 4, dl = t & 15;
#pragma unroll
    for (int it = 0; it < 4; ++it) {
      int j = it * 16 + j16;
      int tg = cc * 64 + j;
      float dtv = 0.f, xv = 0.f;
      if (tg < LQ) {
        int l = dir ? (LQ - 1 - tg) : tg;
        size_t bl = (size_t)(b999 + l);
        dtv = dtp[bl * 512 + d0 + dl];
        xv = xcp[bl * 512 + d0 + dl];
      }
      s_dx[(j * 17 + dl) * 2] = dtv;
      s_dx[(j * 17 + dl) * 2 + 1] = xv;
    }
    int j8 = t >> 5, idx = t & 31;
#pragma unroll
    for (int it = 0; it < 8; ++it) {
      int j = it * 8 + j8;
      int tg = cc * 64 + j;
      float v = 0.f;
      if (tg < LQ) {
        int l = dir ? (LQ - 1 - tg) : tg;
        v = xdp[(size_t)(b999 + l) * 48 + 16 + idx];
      }
      int ss = idx & 15, isC = idx >> 4;
      s_bc[(j * 16 + ss) * 2 + isC] = v;
    }
  };

  // chain over 16 chunks
  float hs0 = 0.f, hs1 = 0.f;
  {
    float h = 0.f;
#pragma unroll
    for (int ccc = 0; ccc < NCHK; ++ccc) {
      if (ccc == c0) hs0 = h;
      if (ccc == c0 + 1) hs1 = h;
      float prv = prod[wbase + ccc * 256 + t];
      float lov = loc[wbase + ccc * 256 + t];
      h = prv * h + lov;
    }
  }

  auto zload = [&](int cc, int j0n) -> float {
    int tg = cc * 64 + j0n + s;
    if (j0n < 64 && tg < LQ) {
      int l = dir ? (LQ - 1 - tg) : tg;
      return zp[(size_t)(b999 + l) * 2048];
    }
    return 0.f;
  };

#pragma unroll
  for (int ci = 0; ci < 2; ++ci) {
    int cc = c0 + ci;
    stage(cc);
    __syncthreads();
    float h = ci ? hs1 : hs0;
    float keepP = 0.f;
    float zq = zload(cc, 0);
    for (int j0 = 0; j0 < 64; j0 += 16) {
#pragma unroll
      for (int jj = 0; jj < 16; ++jj) {
        int j = j0 + jj;
        float2 dx = *(float2*)&s_dx[(j * 17 + dloc) * 2];
        float2 bc = *(float2*)&s_bc[(j * 16 + s) * 2];
        float dA = exp2f(dx.x * a2);
        h = dA * h + dx.x * dx.y * bc.x;
        float p = h * bc.y;
        p += __shfl_xor(p, 1, 16);
        p += __shfl_xor(p, 2, 16);
        p += __shfl_xor(p, 4, 16);
        p += __shfl_xor(p, 8, 16);
        if (jj == s) keepP = p;
      }
      int tg = cc * 64 + j0 + s;
      float xv = s_dx[((j0 + s) * 17 + dloc) * 2 + 1];
      float zv = zq;
      zq = zload(cc, j0 + 16);
      float sig = 1.f / (1.f + __expf(-zv));
      float y = (keepP + xv * Dd) * (zv * sig);
      if (tg < LQ) {
        int l = dir ? (LQ - 1 - tg) : tg;
        gp[(size_t)(b999 + l) * 512 + d] = f2bf(y);
      }
    }
    __syncthreads();
  }
}

// -------------------- decoder as GEMM + combine --------------------
__global__ __launch_bounds__(256) void k_zg(const float* __restrict__ Mt,
                                            const float* __restrict__ dw,
                                            float* __restrict__ Z) {
  __shared__ float sm[16][260];
  __shared__ float sw[256][16];
  int t = threadIdx.x;
  int b = blockIdx.x >= 63;
  int r0 = (blockIdx.x - b * 63) * 16;
#pragma unroll
  for (int it = 0; it < 16; ++it) {
    int e = it * 256 + t;
    int r = e >> 8, c = e & 255;
    int l = r0 + r;
    sm[r][c] = (l < LQ) ? Mt[(size_t)(b * LQ + l) * 256 + c] : 0.f;
    sw[e >> 4][e & 15] = dw[e];
  }
  __syncthreads();
  int lrow = t >> 4, j = t & 15;
  float acc = 0.f;
#pragma unroll 8
  for (int n = 0; n < 256; ++n) acc += sm[lrow][n] * sw[n][j];
  int l = r0 + lrow;
  Z[(size_t)(b * 1008 + l) * 16 + j] = acc;
}

__global__ __launch_bounds__(256) void k_comb(const float* __restrict__ Z,
                                              float* __restrict__ out) {
  int idx = blockIdx.x * 256 + threadIdx.x;
  if (idx >= 16000) return;
  int b = idx >= 8000;
  int tt = idx - b * 8000;
  int l0 = tt >> 3, j0 = tt & 7;
  float v = 0.f;
  if (l0 <= LQ - 1) v += Z[(size_t)(b * 1008 + l0) * 16 + j0];
  if (l0 >= 1) v += Z[(size_t)(b * 1008 + l0 - 1) * 16 + j0 + 8];
  out[idx] = v;
}

// ==================== launch ====================
extern "C" void kernel_launch(void* const* d_in, const int* in_sizes, int n_in,
                              void* d_out, int out_size, void* d_ws, size_t ws_size,
                              hipStream_t stream) {
  const float* mixture = (const float*)d_in[0];
  const float* enc_w = (const float*)d_in[1];
  const float* dec_w = (const float*)d_in[2];
  const float* gn_w = (const float*)d_in[3];
  const float* gn_b = (const float*)d_in[4];
  const float* bot_w = (const float*)d_in[5];
  const float* bot_b = (const float*)d_in[6];
  const float* blk_norm_w = (const float*)d_in[7];
  const float* in_w = (const float*)d_in[8];
  const float* conv_w = (const float*)d_in[9];
  const float* conv_b = (const float*)d_in[10];
  const float* xproj_w = (const float*)d_in[11];
  const float* dt_w = (const float*)d_in[12];
  const float* dt_b = (const float*)d_in[13];
  const float* A_log = (const float*)d_in[14];
  const float* Dmat = (const float*)d_in[15];
  const float* out_w = (const float*)d_in[16];
  const float* normf_w = (const float*)d_in[17];
  const float* mask_w = (const float*)d_in[18];
  const float* mask_b = (const float*)d_in[19];
  float* outp = (float*)d_out;

  float* W = (float*)d_ws;
  size_t off = 0;
  auto alloc = [&](size_t n) {
    float* p = W + off;
    off += (n + 255) & ~(size_t)255;
    return p;
  };
  float* stats = alloc(8);
  float* pp = alloc(4096);            // per-block groupnorm partials
  float* w2 = alloc(65536);
  float* cc = alloc(512);
  float* mw = alloc(511488);          // [b][n][l]
  float* x = alloc(511488);           // [bl][256]
  float* xn = alloc(511488);          // fp32 (final rms only)
  float* xzb = alloc(4091904);        // [bl][2048]
  float* xcb = alloc(2045952);        // [dir][bl][512]
  float* xdblb = alloc(191808);       // [dir][bl][48]
  float* dtgb = alloc(2045952);       // [dir][bl][512]
  float* maskedb = alloc(511488);     // masked_t [bl][256]
  float* prodb = alloc(524288);
  float* locb = alloc(524288);
  float* zbuf = alloc(32256);         // [2][1008][16]
  float* dtwt = alloc(131072);        // transposed dt weights [w][q][512]
  ushort* xnh = (ushort*)alloc(255744);
  ushort* ghb = (ushort*)alloc(1022976);
  ushort* inwh = (ushort*)alloc(2097152);
  ushort* outwh = (ushort*)alloc(1048576);

  k_quant<<<16384, 256, 0, stream>>>(in_w, out_w, dt_w, inwh, outwh, dtwt);
  k_enc<<<1998, 256, 0, stream>>>(mixture, enc_w, mw, pp);
  k_stats<<<2, 256, 0, stream>>>(pp, stats);
  k_prep<<<256, 256, 0, stream>>>(bot_w, gn_w, gn_b, bot_b, stats, w2, cc);
  gemm64<0><<<dim3(32, 4, 1), 256, 0, stream>>>(mw, w2, x, stats, cc, BLQ, 256);

  for (int i = 0; i < 8; ++i) {
    k_rms<true><<<500, 256, 0, stream>>>(x, blk_norm_w + i * 256, nullptr, xnh);
    k_mm1<<<dim3(16, 16), 256, 0, stream>>>(xnh, inwh + (size_t)i * 524288, xzb);
    k_conv<<<dim3(3996, 2, 1), 256, 0, stream>>>(xzb, conv_w, conv_b, xcb, i);
    hipMemsetAsync(xdblb, 0, 191808 * sizeof(float), stream);
    k_xprojK<<<dim3(32, 4, 2), 256, 0, stream>>>(
        xcb, xproj_w + (size_t)i * 2 * 48 * 512, xdblb, i);
    k_dt<<<dim3(3996, 2, 1), 256, 0, stream>>>(xdblb, dtwt, dt_b, dtgb, i);
    k_scanA<<<1024, 256, 0, stream>>>(dtgb, xcb, xdblb, A_log, prodb, locb, i);
    k_scanC<<<1024, 256, 0, stream>>>(dtgb, xcb, xdblb, xzb, A_log, Dmat,
                                      prodb, locb, ghb, i);
    k_mm2<<<dim3(16, 2), 256, 0, stream>>>(ghb, outwh + (size_t)i * 262144, x);
  }

  k_rms<false><<<500, 256, 0, stream>>>(x, normf_w, xn, nullptr);
  gemm64<3><<<dim3(32, 4, 1), 256, 0, stream>>>(xn, mask_w, maskedb, mask_b, mw, BLQ, 256);
  k_zg<<<126, 256, 0, stream>>>(maskedb, dec_w, zbuf);
  k_comb<<<63, 256, 0, stream>>>(zbuf, outp);
}